// Round 1
// baseline (576.174 us; speedup 1.0000x reference)
//
#include <hip/hip_runtime.h>
#include <math.h>

#define T_STEPS 1440
#define KCH 30            // active chunks per sequence (lanes 0..29 of each 32-lane group)
#define CHUNK 48          // timesteps per chunk  (30*48 = 1440)
#define GRP 8             // load-staging depth
#define NGRP (CHUNK/GRP)  // 6

__device__ __forceinline__ float sigf(float x) { return 1.0f / (1.0f + expf(-x)); }

__global__ __launch_bounds__(256, 3) void rc_scan_kernel(
    const float4* __restrict__ in,
    const float* __restrict__ p_ri, const float* __restrict__ p_re,
    const float* __restrict__ p_ci, const float* __restrict__ p_ce,
    const float* __restrict__ p_ai, const float* __restrict__ p_ae,
    const float* __restrict__ p_hg,
    float* __restrict__ out)
{
    const int tid = blockIdx.x * blockDim.x + threadIdx.x;
    const int c   = tid & 31;   // chunk index within sequence
    const int s   = tid >> 5;   // sequence index
    if (c >= KCH) return;       // 2 idle lanes per 32-lane group (never sourced by shfl)

    // sigmoid-bounded params (uniform across all threads)
    const float Ri = 1.0e-4f + (0.2f - 1.0e-4f) * sigf(p_ri[0]);
    const float Re = 1.0e-4f + (0.2f - 1.0e-4f) * sigf(p_re[0]);
    const float Ci = 1.0e5f + (1.0e8f - 1.0e5f) * sigf(p_ci[0]);
    const float Ce = 1.0e5f + (1.0e8f - 1.0e5f) * sigf(p_ce[0]);
    const float Ai = 0.2f * sigf(p_ai[0]);
    const float Ae = 0.2f * sigf(p_ae[0]);
    const float hg = 1.0f + (20000.0f - 1.0f) * sigf(p_hg[0]);

    const float DT = 300.0f;
    const float a1  = DT / (Ri * Ci);
    const float b1  = DT / (Ri * Ce);
    const float b2  = DT / (Re * Ce);
    const float ksi = DT * Ai / Ci;
    const float kse = DT * Ae / Ce;
    const float kh  = -DT * hg / Ci;   // MODE_COOL => cooling_sign = -1

    const float4* p = in + (size_t)s * T_STEPS + (size_t)c * CHUNK;

    // ---------- pass 1: particular trajectory from zero init ----------
    // chunk 0 seeds the TRUE initial state -> its outputs are exact (no fixup)
    float pi = 0.0f, pe = 0.0f;
    float po[CHUNK];
    float4 bA[GRP], bB[GRP];

#pragma unroll
    for (int j = 0; j < GRP; ++j) bA[j] = p[j];
#pragma unroll
    for (int j = 0; j < GRP; ++j) bB[j] = p[GRP + j];
    if (c == 0) { pi = bA[0].x; pe = 0.5f * (bA[0].x + bA[0].y); }

#pragma unroll
    for (int gp = 0; gp < NGRP; gp += 2) {
        // compute group gp from bA, prefetch group gp+2 into bA
#pragma unroll
        for (int j = 0; j < GRP; ++j) {
            float4 x = bA[j];
            float nti = fmaf(a1, pe - pi, pi);
            nti = fmaf(ksi, x.w, nti);
            nti = fmaf(kh,  x.z, nti);
            float nte = fmaf(b1, pi - pe, pe);
            nte = fmaf(b2, x.y - pe, nte);
            nte = fmaf(kse, x.w, nte);
            pi = nti; pe = nte;
            po[gp * GRP + j] = nti;
        }
        if (gp + 2 < NGRP) {
            const float4* q = p + (gp + 2) * GRP;
#pragma unroll
            for (int j = 0; j < GRP; ++j) bA[j] = q[j];
        }
        // compute group gp+1 from bB, prefetch group gp+3 into bB
#pragma unroll
        for (int j = 0; j < GRP; ++j) {
            float4 x = bB[j];
            float nti = fmaf(a1, pe - pi, pi);
            nti = fmaf(ksi, x.w, nti);
            nti = fmaf(kh,  x.z, nti);
            float nte = fmaf(b1, pi - pe, pe);
            nte = fmaf(b2, x.y - pe, nte);
            nte = fmaf(kse, x.w, nte);
            pi = nti; pe = nte;
            po[(gp + 1) * GRP + j] = nti;
        }
        if (gp + 3 < NGRP) {
            const float4* q = p + (gp + 3) * GRP;
#pragma unroll
            for (int j = 0; j < GRP; ++j) bB[j] = q[j];
        }
    }

    // ---------- chunk transfer matrices: A^CHUNK and its squarings ----------
    // A = [[1-a1, a1], [b1, 1-b1-b2]]  (state map for one step, zero inputs)
    const float a00 = 1.0f - a1, a01 = a1, a10 = b1, a11 = 1.0f - b1 - b2;
    float m00 = 1.0f, m01 = 0.0f, m10 = 0.0f, m11 = 1.0f;
    for (int i = 0; i < CHUNK; ++i) {
        float t00 = fmaf(a00, m00, a01 * m10);
        float t01 = fmaf(a00, m01, a01 * m11);
        float t10 = fmaf(a10, m00, a11 * m10);
        float t11 = fmaf(a10, m01, a11 * m11);
        m00 = t00; m01 = t01; m10 = t10; m11 = t11;
    }
    float q00[5], q01[5], q10[5], q11[5];
    q00[0] = m00; q01[0] = m01; q10[0] = m10; q11[0] = m11;
#pragma unroll
    for (int k = 1; k < 5; ++k) {
        q00[k] = fmaf(q00[k-1], q00[k-1], q01[k-1] * q10[k-1]);
        q01[k] = fmaf(q00[k-1], q01[k-1], q01[k-1] * q11[k-1]);
        q10[k] = fmaf(q10[k-1], q00[k-1], q11[k-1] * q10[k-1]);
        q11[k] = fmaf(q10[k-1], q01[k-1], q11[k-1] * q11[k-1]);
    }

    // ---------- affine prefix scan over chunks (Hillis-Steele, width 32) ----------
    // lane c ends with D_c = true state after chunk c (lane 0 carried true init)
    float di = pi, de = pe;
#pragma unroll
    for (int k = 0; k < 5; ++k) {
        const int o = 1 << k;
        float oi = __shfl_up(di, (unsigned)o, 32);
        float oe = __shfl_up(de, (unsigned)o, 32);
        if (c >= o) {
            float ndi = fmaf(q00[k], oi, fmaf(q01[k], oe, di));
            float nde = fmaf(q10[k], oi, fmaf(q11[k], oe, de));
            di = ndi; de = nde;
        }
    }
    // homogeneous initial state for this chunk = D_{c-1} (zero for chunk 0)
    float hi = 0.0f, he = 0.0f;
    {
        float xi = __shfl_up(di, 1u, 32);
        float xe = __shfl_up(de, 1u, 32);
        if (c > 0) { hi = xi; he = xe; }
    }

    // ---------- fixup: add homogeneous response, write aligned float4 ----------
#pragma unroll
    for (int j = 0; j < CHUNK; ++j) {
        float nhi = fmaf(a1, he - hi, hi);
        float nhe = fmaf(b2, -he, fmaf(b1, hi - he, he));
        hi = nhi; he = nhe;
        po[j] += hi;
    }
    float4* ob = reinterpret_cast<float4*>(out + (size_t)s * T_STEPS + (size_t)c * CHUNK);
#pragma unroll
    for (int v = 0; v < CHUNK / 4; ++v)
        ob[v] = make_float4(po[4*v], po[4*v+1], po[4*v+2], po[4*v+3]);
}

extern "C" void kernel_launch(void* const* d_in, const int* in_sizes, int n_in,
                              void* d_out, int out_size, void* d_ws, size_t ws_size,
                              hipStream_t stream) {
    const float4* in = (const float4*)d_in[0];
    const float* p_ri = (const float*)d_in[1];
    const float* p_re = (const float*)d_in[2];
    const float* p_ci = (const float*)d_in[3];
    const float* p_ce = (const float*)d_in[4];
    const float* p_ai = (const float*)d_in[5];
    const float* p_ae = (const float*)d_in[6];
    const float* p_hg = (const float*)d_in[7];
    float* out = (float*)d_out;

    const int B = in_sizes[0] / (T_STEPS * 4);   // 16384
    const int block = 256;                        // 8 sequences per block
    const int grid = (B * 32) / block;            // 2048 blocks

    rc_scan_kernel<<<grid, block, 0, stream>>>(in, p_ri, p_re, p_ci, p_ce,
                                               p_ai, p_ae, p_hg, out);
}